// Round 2
// baseline (690.589 us; speedup 1.0000x reference)
//
#include <hip/hip_runtime.h>

typedef float v4f __attribute__((ext_vector_type(4)));

constexpr int N_ATOMS = 64;
constexpr int NC2 = N_ATOMS * (N_ATOMS - 1) / 2;  // 2016
constexpr int BATCH = 32768;

// One block per batch row. Build the full symmetrized 64x64 matrix in LDS
// (with a per-row quad-rotation swizzle to spread mirrored-write banks),
// then stream it out with aligned float4 non-temporal stores.
//
// LDS layout: element (i,j) lives at sm[i*64 + ((j + 4*i) & 63)].
// Rotation is a multiple of 4, so each output quad (i, 4*jq..4*jq+3) is a
// single aligned float4 at quad index ((jq + i) & 15) of row i.
__global__ __launch_bounds__(256) void triangle_kernel(
    const float* __restrict__ in, float* __restrict__ out) {
    __shared__ float sm[N_ATOMS * 64];  // 16 KB

    const int b = blockIdx.x;
    const int t = threadIdx.x;

    // Zero the diagonal: (i,i) sits at slot (i + 4*i) & 63 = (5*i) & 63.
    // Scatters below never touch diagonal slots, so no race.
    if (t < N_ATOMS) {
        sm[t * 64 + ((5 * t) & 63)] = 0.0f;
    }

    // --- Scatter input into both triangles of the LDS matrix ---
    const v4f* in4 = reinterpret_cast<const v4f*>(in + (size_t)b * NC2);
#pragma unroll
    for (int it = 0; it < 2; ++it) {
        int idx = it * 256 + t;  // float4 index, [0, 504)
        if (idx < NC2 / 4) {
            v4f v = in4[idx];
            int p = idx * 4;  // flat strict-lower index of first element
            // Inverse triangular: largest i with i*(i-1)/2 <= p
            int i = (int)((1.0f + sqrtf(8.0f * (float)p + 1.0f)) * 0.5f);
            if (i * (i - 1) / 2 > p) --i;          // sqrt rounding guards
            if ((i + 1) * i / 2 <= p) ++i;
            int j = p - i * (i - 1) / 2;
#pragma unroll
            for (int k = 0; k < 4; ++k) {
                float val = v[k];
                sm[i * 64 + ((j + 4 * i) & 63)] = val;  // lower (i,j)
                sm[j * 64 + ((i + 4 * j) & 63)] = val;  // mirror (j,i)
                ++j;
                if (j == i) { ++i; j = 0; }  // advance to next flat index
            }
        }
    }
    __syncthreads();

    // --- Stream out: 1024 float4 quads, branch-free, coalesced, nt ---
    float* outp = out + (size_t)b * N_ATOMS * N_ATOMS;
    const v4f* sm4 = reinterpret_cast<const v4f*>(sm);
    v4f* out4 = reinterpret_cast<v4f*>(outp);
#pragma unroll
    for (int it = 0; it < 4; ++it) {
        int q = it * 256 + t;   // output quad index [0, 1024)
        int i = q >> 4;         // row
        int jq = q & 15;        // quad within row
        v4f v = sm4[i * 16 + ((jq + i) & 15)];
        __builtin_nontemporal_store(v, out4 + q);
    }
}

extern "C" void kernel_launch(void* const* d_in, const int* in_sizes, int n_in,
                              void* d_out, int out_size, void* d_ws, size_t ws_size,
                              hipStream_t stream) {
    const float* in = (const float*)d_in[0];
    float* out = (float*)d_out;
    triangle_kernel<<<BATCH, 256, 0, stream>>>(in, out);
}